// Round 4
// baseline (157.997 us; speedup 1.0000x reference)
//
#include <hip/hip_runtime.h>
#include <hip/hip_bf16.h>
#include <stdint.h>

#define OUTN 4096
#define INN  4096
#define SPECN 512
#define BK 64
#define KT (OUTN / BK)   // 64

typedef __attribute__((ext_vector_type(8))) short short8;
typedef __attribute__((ext_vector_type(4))) float f32x4;

__device__ __forceinline__ ushort f2bf(float f) {
    uint32_t u = __float_as_uint(f);
    uint32_t r = (u + 0x7FFFu + ((u >> 16) & 1u)) >> 16;
    return (ushort)r;
}
__device__ __forceinline__ float bf2f(ushort u) {
    return __uint_as_float((uint32_t)u << 16);
}

// ---------------------------------------------------------------------------
// prep: blocks [0,512) build A1/A2 (bf16) + ubias + rowmask (bitmask of
// k-blocks with nonzero simplex coeff, per s-row, no atomics).
// Blocks [512, 4608) transpose+convert W (f32 [o][i]) -> WT (bf16 [i][o]).
// ---------------------------------------------------------------------------
__global__ __launch_bounds__(256) void prep(
    const float* __restrict__ uA, const float* __restrict__ W,
    const float* __restrict__ Bias, const float* __restrict__ Lb,
    const float* __restrict__ Ub, const float* __restrict__ Alpha,
    ushort* __restrict__ A1, ushort* __restrict__ A2, ushort* __restrict__ WT,
    unsigned long long* __restrict__ rowmask, float* __restrict__ ubias_out)
{
    const int tid = threadIdx.x;
    if (blockIdx.x < 512) {
        // ----- build path -----
        const int s = blockIdx.x;
        float acc = 0.f;
        unsigned long long msk = 0;
        for (int p = 0; p < 4; ++p) {
            const int o = p * 1024 + tid * 4;
            const float4 u4 = *(const float4*)&uA[(size_t)s * OUTN + o];
            const float4 lb4 = *(const float4*)&Lb[o];
            const float4 ub4 = *(const float4*)&Ub[o];
            const float4 b4 = *(const float4*)&Bias[o];
            const float4 a4 = *(const float4*)&Alpha[o];
            const float uu[4] = {u4.x, u4.y, u4.z, u4.w};
            const float lbv[4] = {lb4.x, lb4.y, lb4.z, lb4.w};
            const float ubv[4] = {ub4.x, ub4.y, ub4.z, ub4.w};
            const float bv[4] = {b4.x, b4.y, b4.z, b4.w};
            const float av[4] = {a4.x, a4.y, a4.z, a4.w};
            ushort r1[4], r2[4];
#pragma unroll
            for (int j = 0; j < 4; ++j) {
                const float u = uu[j], lb = lbv[j], ub = ubv[j], b = bv[j], a = av[j];
                const float pp = fmaxf(u, 0.f), nn = fminf(u, 0.f);
                const bool stneg = (ub <= 0.f);
                const bool stpos = (lb >= 0.f);
                const float lower_d = (fabsf(lb) >= fabsf(ub)) ? 1.f : 0.f;
                float lbr = fminf(lb, 0.f);
                float ubr = fmaxf(ub, 0.f);
                ubr = fmaxf(ubr, lbr + 1e-8f);
                const float ud = ubr / (ubr - lbr);
                const float upb = -lbr * ud;
                const float ldc = (ud > 0.5f) ? 1.f : 0.f;
                const float oma = 1.f - a;
                const float crown = ud * pp + ldc * nn;
                const float wcoef = a * crown +
                    oma * (stneg ? 0.f : (stpos ? (pp + nn) : lower_d * nn));
                const float scoef = (stneg || stpos) ? 0.f : oma * pp;
                const float ub_t = stneg ? 0.f : (stpos ? b : fmaxf(b, 0.f));
                const float lb_t = stneg ? 0.f : (stpos ? b : lower_d * b);
                acc += pp * (oma * ub_t + upb) + nn * (oma * lb_t) + crown * (a * b);
                r1[j] = f2bf(wcoef);
                r2[j] = f2bf(scoef);
            }
            *(ushort4*)&A1[(size_t)s * OUTN + o] = make_ushort4(r1[0], r1[1], r1[2], r1[3]);
            *(ushort4*)&A2[(size_t)s * OUTN + o] = make_ushort4(r2[0], r2[1], r2[2], r2[3]);
            if (((r2[0] | r2[1] | r2[2] | r2[3]) & 0x7FFF) != 0)
                msk |= 1ull << (p * 16 + (tid >> 4));
        }
#pragma unroll
        for (int off = 32; off; off >>= 1) {
            acc += __shfl_down(acc, off);
            msk |= __shfl_down(msk, off);
        }
        __shared__ float redf[4];
        __shared__ unsigned long long redm[4];
        if ((tid & 63) == 0) { redf[tid >> 6] = acc; redm[tid >> 6] = msk; }
        __syncthreads();
        if (tid == 0) {
            ubias_out[s] = redf[0] + redf[1] + redf[2] + redf[3];
            rowmask[s] = redm[0] | redm[1] | redm[2] | redm[3];
        }
    } else {
        // ----- transpose path -----
        __shared__ float t[64][65];
        const int tb = blockIdx.x - 512;
        const int bi = tb & 63, bo = tb >> 6;
        const int i0 = bi * 64, o0 = bo * 64;
        const int sub = tid >> 4;        // 0..15
        const int q4 = (tid & 15) * 4;   // 0..60
#pragma unroll
        for (int p = 0; p < 4; ++p) {
            const int ol = p * 16 + sub;
            const float4 w = *(const float4*)&W[(size_t)(o0 + ol) * INN + i0 + q4];
            t[q4 + 0][ol] = w.x;
            t[q4 + 1][ol] = w.y;
            t[q4 + 2][ol] = w.z;
            t[q4 + 3][ol] = w.w;
        }
        __syncthreads();
#pragma unroll
        for (int p = 0; p < 4; ++p) {
            const int il = p * 16 + sub;
            *(ushort4*)&WT[(size_t)(i0 + il) * OUTN + o0 + q4] =
                make_ushort4(f2bf(t[il][q4]), f2bf(t[il][q4 + 1]),
                             f2bf(t[il][q4 + 2]), f2bf(t[il][q4 + 3]));
        }
    }
}

// ---------------------------------------------------------------------------
// gemm: uA[s,i] = A1[s,:]·WT[i,:] (+ A2·S^T on flagged k-blocks, S computed
// on the fly). BM=BN=64, BK=64; 3-buffer, depth-2 prefetch pipeline with
// counted vmcnt (never drains to 0 in the main loop) + raw s_barrier.
// Per wave per stage: exactly 4 global_load_lds -> vmcnt(4) certifies the
// oldest tile (in-order retirement). Source-swizzled staging (chunk ^= row&7)
// keeps ds_read_b128 fragment reads conflict-free (round-1 verified, 0 conf).
// ---------------------------------------------------------------------------
__global__ __launch_bounds__(256) void gemm(
    const ushort* __restrict__ A1, const ushort* __restrict__ A2,
    const ushort* __restrict__ WT, const float* __restrict__ Bias,
    const unsigned long long* __restrict__ rowmask, float* __restrict__ outp)
{
    __shared__ ushort sA[3][64 * 64];
    __shared__ ushort sB[3][64 * 64];

    // bx-major so 8 consecutive blocks share a WT panel; XCD-chunked swizzle.
    const int bid = blockIdx.x;
    const int swz = (bid & 7) * 64 + (bid >> 3);
    const int bx = swz >> 3;   // i tile 0..63
    const int by = swz & 7;    // s tile 0..7
    const int i0 = bx * 64, s0 = by * 64;
    const int tid = threadIdx.x;
    const int lane = tid & 63;
    const int w = tid >> 6;
    const int wr = w >> 1, wc = w & 1;

    // block simplex mask: per-wave butterfly OR (no LDS, no barrier needed)
    unsigned long long smask = rowmask[s0 + lane];
#pragma unroll
    for (int off = 32; off; off >>= 1) smask |= __shfl_xor(smask, off);

    f32x4 acc[2][2] = {};

    // staging: 8KB tile = 8 chunks of 1KB; wave w owns chunks 2w, 2w+1 of
    // each matrix (4 loads/wave/stage). chunk c covers rows c*8..c*8+7;
    // lane l -> row c*8 + (l>>3), slot l&7 holds global 16B-chunk
    // ((l&7) ^ (row&7)).
    const int c0 = w * 2, c1 = w * 2 + 1;
    const int rr0 = c0 * 8 + (lane >> 3), rr1 = c1 * 8 + (lane >> 3);
    const int g0 = (lane & 7) ^ (rr0 & 7), g1 = (lane & 7) ^ (rr1 & 7);

    auto stage = [&](int buf, int t) {
        const int ko = t * BK;
        __builtin_amdgcn_global_load_lds(
            (const __attribute__((address_space(1))) void*)(A1 + (size_t)(s0 + rr0) * OUTN + ko + g0 * 8),
            (__attribute__((address_space(3))) void*)&sA[buf][c0 * 512], 16, 0, 0);
        __builtin_amdgcn_global_load_lds(
            (const __attribute__((address_space(1))) void*)(A1 + (size_t)(s0 + rr1) * OUTN + ko + g1 * 8),
            (__attribute__((address_space(3))) void*)&sA[buf][c1 * 512], 16, 0, 0);
        __builtin_amdgcn_global_load_lds(
            (const __attribute__((address_space(1))) void*)(WT + (size_t)(i0 + rr0) * OUTN + ko + g0 * 8),
            (__attribute__((address_space(3))) void*)&sB[buf][c0 * 512], 16, 0, 0);
        __builtin_amdgcn_global_load_lds(
            (const __attribute__((address_space(1))) void*)(WT + (size_t)(i0 + rr1) * OUTN + ko + g1 * 8),
            (__attribute__((address_space(3))) void*)&sB[buf][c1 * 512], 16, 0, 0);
    };

    auto compute = [&](int buf) {
#pragma unroll
        for (int kk = 0; kk < BK; kk += 32) {
            short8 av[2], bv[2];
#pragma unroll
            for (int m = 0; m < 2; ++m) {
                const int r = wr * 32 + m * 16 + (lane & 15);
                const int g = ((kk >> 3) + (lane >> 4)) ^ (r & 7);
                av[m] = *(const short8*)&sA[buf][r * 64 + g * 8];
            }
#pragma unroll
            for (int n = 0; n < 2; ++n) {
                const int r = wc * 32 + n * 16 + (lane & 15);
                const int g = ((kk >> 3) + (lane >> 4)) ^ (r & 7);
                bv[n] = *(const short8*)&sB[buf][r * 64 + g * 8];
            }
#pragma unroll
            for (int m = 0; m < 2; ++m)
#pragma unroll
                for (int n = 0; n < 2; ++n)
                    acc[m][n] = __builtin_amdgcn_mfma_f32_16x16x32_bf16(
                        av[m], bv[n], acc[m][n], 0, 0, 0);
        }
    };

    // prologue: 2 tiles in flight (8 loads/wave)
    stage(0, 0);
    stage(1, 1);
    for (int t = 0; t < KT - 1; ++t) {
        // wait own tile-t loads (oldest 4), keep tile t+1's 4 in flight
        asm volatile("s_waitcnt vmcnt(4)" ::: "memory");
        __builtin_amdgcn_sched_barrier(0);
        __builtin_amdgcn_s_barrier();
        // buf (t+2)%3 was consumed at tile t-1; every wave passed that
        // consumption before this barrier -> safe to overwrite now.
        if (t + 2 < KT) stage((t + 2) % 3, t + 2);
        compute(t % 3);
    }
    asm volatile("s_waitcnt vmcnt(0)" ::: "memory");
    __builtin_amdgcn_sched_barrier(0);
    __builtin_amdgcn_s_barrier();
    compute((KT - 1) % 3);

    // rare path: simplex contribution for flagged 64-wide k-blocks.
    if (smask) {
        for (int b = 0; b < 64; ++b) {
            if (!((smask >> b) & 1)) continue;
            __syncthreads();            // buffers free to overwrite (full drain ok, cold path)
            stage(0, b);                // A2? no: need A2 -- custom below
            // overwrite sA[0] with A2 instead (stage() loaded A1; redo A rows)
            __builtin_amdgcn_global_load_lds(
                (const __attribute__((address_space(1))) void*)(A2 + (size_t)(s0 + rr0) * OUTN + b * 64 + g0 * 8),
                (__attribute__((address_space(3))) void*)&sA[0][c0 * 512], 16, 0, 0);
            __builtin_amdgcn_global_load_lds(
                (const __attribute__((address_space(1))) void*)(A2 + (size_t)(s0 + rr1) * OUTN + b * 64 + g1 * 8),
                (__attribute__((address_space(3))) void*)&sA[0][c1 * 512], 16, 0, 0);
            __syncthreads();
#pragma unroll
            for (int kk = 0; kk < 64; kk += 32) {
                short8 av2[2], bw[2];
#pragma unroll
                for (int m = 0; m < 2; ++m) {
                    const int r = wr * 32 + m * 16 + (lane & 15);
                    const int g = ((kk >> 3) + (lane >> 4)) ^ (r & 7);
                    av2[m] = *(const short8*)&sA[0][r * 64 + g * 8];
                }
                const int kb = kk + (lane >> 4) * 8;
                const float4 b0 = *(const float4*)&Bias[b * 64 + kb];
                const float4 b1 = *(const float4*)&Bias[b * 64 + kb + 4];
                const float bb[8] = {b0.x, b0.y, b0.z, b0.w, b1.x, b1.y, b1.z, b1.w};
#pragma unroll
                for (int n = 0; n < 2; ++n) {
                    const int r = wc * 32 + n * 16 + (lane & 15);
                    const int g = ((kk >> 3) + (lane >> 4)) ^ (r & 7);
                    const short8 wv = *(const short8*)&sB[0][r * 64 + g * 8];
                    short8 sv;
#pragma unroll
                    for (int j = 0; j < 8; ++j) {
                        const float wf = bf2f((ushort)wv[j]);
                        sv[j] = (short)f2bf(fmaxf(wf + bb[j], 0.f) - fmaxf(bb[j], 0.f));
                    }
                    bw[n] = sv;
                }
#pragma unroll
                for (int m = 0; m < 2; ++m)
#pragma unroll
                    for (int n = 0; n < 2; ++n)
                        acc[m][n] = __builtin_amdgcn_mfma_f32_16x16x32_bf16(
                            av2[m], bw[n], acc[m][n], 0, 0, 0);
            }
        }
    }

    // C/D layout: col = lane&15, row = (lane>>4)*4 + reg   [m89/m91 verified]
#pragma unroll
    for (int m = 0; m < 2; ++m)
#pragma unroll
        for (int n = 0; n < 2; ++n) {
            const int srow = s0 + wr * 32 + m * 16 + (lane >> 4) * 4;
            const int icol = i0 + wc * 32 + n * 16 + (lane & 15);
#pragma unroll
            for (int r = 0; r < 4; ++r)
                outp[(size_t)(srow + r) * INN + icol] = acc[m][n][r];
        }
}

// ---------------------------------------------------------------------------
extern "C" void kernel_launch(void* const* d_in, const int* in_sizes, int n_in,
                              void* d_out, int out_size, void* d_ws, size_t ws_size,
                              hipStream_t stream) {
    const float* uA    = (const float*)d_in[0];
    const float* W     = (const float*)d_in[1];
    const float* Bias  = (const float*)d_in[2];
    const float* Lb    = (const float*)d_in[3];
    const float* Ub    = (const float*)d_in[4];
    const float* Alpha = (const float*)d_in[5];
    float* outp = (float*)d_out;

    char* ws = (char*)d_ws;
    unsigned long long* rowmask = (unsigned long long*)ws;       // 4 KB
    ushort* A1 = (ushort*)(ws + 4096);                           // 4 MB
    ushort* A2 = (ushort*)(ws + 4096 + (1u << 22));              // 4 MB
    ushort* WT = (ushort*)(ws + 4096 + (2u << 22));              // 32 MB

    prep<<<4608, 256, 0, stream>>>(uA, W, Bias, Lb, Ub, Alpha, A1, A2, WT,
                                   rowmask, outp + (size_t)SPECN * INN);
    gemm<<<512, 256, 0, stream>>>(A1, A2, WT, Bias, rowmask, outp);
}

// Round 5
// 145.486 us; speedup vs baseline: 1.0860x; 1.0860x over previous
//
#include <hip/hip_runtime.h>
#include <hip/hip_bf16.h>
#include <stdint.h>

#define OUTN 4096
#define INN  4096
#define SPECN 512
#define BK 128
#define KT (OUTN / BK)   // 32

typedef __attribute__((ext_vector_type(8))) short short8;
typedef __attribute__((ext_vector_type(4))) float f32x4;

__device__ __forceinline__ ushort f2bf(float f) {
    uint32_t u = __float_as_uint(f);
    uint32_t r = (u + 0x7FFFu + ((u >> 16) & 1u)) >> 16;
    return (ushort)r;
}
__device__ __forceinline__ float bf2f(ushort u) {
    return __uint_as_float((uint32_t)u << 16);
}

// ---------------------------------------------------------------------------
// prep: blocks [0,512) build A1/A2 (bf16) + ubias + rowmask (bitmask of
// 64-wide k-blocks with nonzero simplex coeff per s-row, no atomics).
// Blocks [512, 4608) transpose+convert W (f32 [o][i]) -> WT (bf16 [i][o]).
// ---------------------------------------------------------------------------
__global__ __launch_bounds__(256) void prep(
    const float* __restrict__ uA, const float* __restrict__ W,
    const float* __restrict__ Bias, const float* __restrict__ Lb,
    const float* __restrict__ Ub, const float* __restrict__ Alpha,
    ushort* __restrict__ A1, ushort* __restrict__ A2, ushort* __restrict__ WT,
    unsigned long long* __restrict__ rowmask, float* __restrict__ ubias_out)
{
    const int tid = threadIdx.x;
    if (blockIdx.x < 512) {
        const int s = blockIdx.x;
        float acc = 0.f;
        unsigned long long msk = 0;
        for (int p = 0; p < 4; ++p) {
            const int o = p * 1024 + tid * 4;
            const float4 u4 = *(const float4*)&uA[(size_t)s * OUTN + o];
            const float4 lb4 = *(const float4*)&Lb[o];
            const float4 ub4 = *(const float4*)&Ub[o];
            const float4 b4 = *(const float4*)&Bias[o];
            const float4 a4 = *(const float4*)&Alpha[o];
            const float uu[4] = {u4.x, u4.y, u4.z, u4.w};
            const float lbv[4] = {lb4.x, lb4.y, lb4.z, lb4.w};
            const float ubv[4] = {ub4.x, ub4.y, ub4.z, ub4.w};
            const float bv[4] = {b4.x, b4.y, b4.z, b4.w};
            const float av[4] = {a4.x, a4.y, a4.z, a4.w};
            ushort r1[4], r2[4];
#pragma unroll
            for (int j = 0; j < 4; ++j) {
                const float u = uu[j], lb = lbv[j], ub = ubv[j], b = bv[j], a = av[j];
                const float pp = fmaxf(u, 0.f), nn = fminf(u, 0.f);
                const bool stneg = (ub <= 0.f);
                const bool stpos = (lb >= 0.f);
                const float lower_d = (fabsf(lb) >= fabsf(ub)) ? 1.f : 0.f;
                float lbr = fminf(lb, 0.f);
                float ubr = fmaxf(ub, 0.f);
                ubr = fmaxf(ubr, lbr + 1e-8f);
                const float ud = ubr / (ubr - lbr);
                const float upb = -lbr * ud;
                const float ldc = (ud > 0.5f) ? 1.f : 0.f;
                const float oma = 1.f - a;
                const float crown = ud * pp + ldc * nn;
                const float wcoef = a * crown +
                    oma * (stneg ? 0.f : (stpos ? (pp + nn) : lower_d * nn));
                const float scoef = (stneg || stpos) ? 0.f : oma * pp;
                const float ub_t = stneg ? 0.f : (stpos ? b : fmaxf(b, 0.f));
                const float lb_t = stneg ? 0.f : (stpos ? b : lower_d * b);
                acc += pp * (oma * ub_t + upb) + nn * (oma * lb_t) + crown * (a * b);
                r1[j] = f2bf(wcoef);
                r2[j] = f2bf(scoef);
            }
            *(ushort4*)&A1[(size_t)s * OUTN + o] = make_ushort4(r1[0], r1[1], r1[2], r1[3]);
            *(ushort4*)&A2[(size_t)s * OUTN + o] = make_ushort4(r2[0], r2[1], r2[2], r2[3]);
            if (((r2[0] | r2[1] | r2[2] | r2[3]) & 0x7FFF) != 0)
                msk |= 1ull << (p * 16 + (tid >> 4));
        }
#pragma unroll
        for (int off = 32; off; off >>= 1) {
            acc += __shfl_down(acc, off);
            msk |= __shfl_down(msk, off);
        }
        __shared__ float redf[4];
        __shared__ unsigned long long redm[4];
        if ((tid & 63) == 0) { redf[tid >> 6] = acc; redm[tid >> 6] = msk; }
        __syncthreads();
        if (tid == 0) {
            ubias_out[s] = redf[0] + redf[1] + redf[2] + redf[3];
            rowmask[s] = redm[0] | redm[1] | redm[2] | redm[3];
        }
    } else {
        __shared__ float t[64][65];
        const int tb = blockIdx.x - 512;
        const int bi = tb & 63, bo = tb >> 6;
        const int i0 = bi * 64, o0 = bo * 64;
        const int sub = tid >> 4;
        const int q4 = (tid & 15) * 4;
#pragma unroll
        for (int p = 0; p < 4; ++p) {
            const int ol = p * 16 + sub;
            const float4 w = *(const float4*)&W[(size_t)(o0 + ol) * INN + i0 + q4];
            t[q4 + 0][ol] = w.x;
            t[q4 + 1][ol] = w.y;
            t[q4 + 2][ol] = w.z;
            t[q4 + 3][ol] = w.w;
        }
        __syncthreads();
#pragma unroll
        for (int p = 0; p < 4; ++p) {
            const int il = p * 16 + sub;
            *(ushort4*)&WT[(size_t)(i0 + il) * OUTN + o0 + q4] =
                make_ushort4(f2bf(t[il][q4]), f2bf(t[il][q4 + 1]),
                             f2bf(t[il][q4 + 2]), f2bf(t[il][q4 + 3]));
        }
    }
}

// ---------------------------------------------------------------------------
// gemm, wave-split-K structure: block tile 64(s) x 64(i), BK=128 staged;
// each of the 4 waves computes the FULL 64x64 (4x4 MFMA frags) over its
// private k=32 slice of the tile -> ds_read:MFMA = 1:2 (the 128^2-ladder
// ratio) while grid stays 512 (2 blocks/CU). Wave accs are tree-summed
// through LDS in the epilogue (staging buffers reused, no atomics).
// 2-phase double-buffered staging via source-swizzled global_load_lds w16.
// ---------------------------------------------------------------------------
__global__ __launch_bounds__(256) void gemm(
    const ushort* __restrict__ A1, const ushort* __restrict__ A2,
    const ushort* __restrict__ WT, const float* __restrict__ Bias,
    const unsigned long long* __restrict__ rowmask, float* __restrict__ outp)
{
    // [0]=A, [1]=B, double-buffered 64x128 bf16 tiles; 64 KB total.
    __shared__ __align__(16) ushort smem[2][2][64 * BK];

    const int bid = blockIdx.x;
    const int swz = (bid & 7) * 64 + (bid >> 3);   // XCD-chunked
    const int bx = swz >> 3;   // i tile 0..63
    const int by = swz & 7;    // s tile 0..7
    const int i0 = bx * 64, s0 = by * 64;
    const int tid = threadIdx.x;
    const int lane = tid & 63;
    const int w = tid >> 6;

    unsigned long long smask = rowmask[s0 + lane];
#pragma unroll
    for (int off = 32; off; off >>= 1) smask |= __shfl_xor(smask, off);

    f32x4 acc[4][4] = {};

    // staging: 16KB tile = 16 chunks of 1KB; wave w owns chunks w*4..w*4+3
    // of A and of B (8 global_load_lds per wave per tile). chunk c covers
    // rows c*4..c*4+3 (256B rows); lane l -> row c*4+(l>>4), slot l&15
    // holds global 16B k-chunk ((l&15) ^ (row&15)).
    auto stage = [&](int buf, int t) {
        const int ko = t * BK;
#pragma unroll
        for (int h = 0; h < 4; ++h) {
            const int c = w * 4 + h;
            const int row = c * 4 + (lane >> 4);
            const int g = (lane & 15) ^ (row & 15);
            __builtin_amdgcn_global_load_lds(
                (const __attribute__((address_space(1))) void*)(A1 + (size_t)(s0 + row) * OUTN + ko + g * 8),
                (__attribute__((address_space(3))) void*)&smem[0][buf][c * 512], 16, 0, 0);
            __builtin_amdgcn_global_load_lds(
                (const __attribute__((address_space(1))) void*)(WT + (size_t)(i0 + row) * OUTN + ko + g * 8),
                (__attribute__((address_space(3))) void*)&smem[1][buf][c * 512], 16, 0, 0);
        }
    };

    // wave w consumes k-slice [w*32, w*32+32) of the staged tile.
    auto compute = [&](int buf) {
        const int kc = w * 4 + (lane >> 4);   // 16B k-chunk index 0..15
        short8 av[4], bv[4];
#pragma unroll
        for (int m = 0; m < 4; ++m) {
            const int r = m * 16 + (lane & 15);
            av[m] = *(const short8*)&smem[0][buf][r * BK + (kc ^ (r & 15)) * 8];
        }
#pragma unroll
        for (int n = 0; n < 4; ++n) {
            const int r = n * 16 + (lane & 15);
            bv[n] = *(const short8*)&smem[1][buf][r * BK + (kc ^ (r & 15)) * 8];
        }
#pragma unroll
        for (int m = 0; m < 4; ++m)
#pragma unroll
            for (int n = 0; n < 4; ++n)
                acc[m][n] = __builtin_amdgcn_mfma_f32_16x16x32_bf16(
                    av[m], bv[n], acc[m][n], 0, 0, 0);
    };

    stage(0, 0);
    __syncthreads();
    for (int t = 0; t < KT - 1; ++t) {
        stage((t + 1) & 1, t + 1);   // prefetch next tile (in flight under MFMA)
        compute(t & 1);
        __syncthreads();
    }
    compute((KT - 1) & 1);

    // rare path: simplex contribution for flagged 64-wide k-blocks
    // (A2 . relu(WT+b)-relu(b)); waves 0,1 cover k-slices 0/32.
    if (smask) {
        for (int b = 0; b < 64; ++b) {
            if (!((smask >> b) & 1)) continue;
            __syncthreads();
#pragma unroll
            for (int h = 0; h < 2; ++h) {
                const int c = w * 2 + h;
                const int row = c * 8 + (lane >> 3);
                const int g = (lane & 7) ^ (row & 7);
                __builtin_amdgcn_global_load_lds(
                    (const __attribute__((address_space(1))) void*)(A2 + (size_t)(s0 + row) * OUTN + b * 64 + g * 8),
                    (__attribute__((address_space(3))) void*)&smem[0][0][c * 512], 16, 0, 0);
                __builtin_amdgcn_global_load_lds(
                    (const __attribute__((address_space(1))) void*)(WT + (size_t)(i0 + row) * OUTN + b * 64 + g * 8),
                    (__attribute__((address_space(3))) void*)&smem[1][0][c * 512], 16, 0, 0);
            }
            __syncthreads();
            if (w < 2) {
                const int kk = w * 32;
                const int kc8 = (kk >> 3) + (lane >> 4);
                short8 av2[4], bw[4];
#pragma unroll
                for (int m = 0; m < 4; ++m) {
                    const int r = m * 16 + (lane & 15);
                    av2[m] = *(const short8*)&smem[0][0][r * 64 + (kc8 ^ (r & 7)) * 8];
                }
                const int kb = kk + (lane >> 4) * 8;
                const float4 b0 = *(const float4*)&Bias[b * 64 + kb];
                const float4 b1 = *(const float4*)&Bias[b * 64 + kb + 4];
                const float bb[8] = {b0.x, b0.y, b0.z, b0.w, b1.x, b1.y, b1.z, b1.w};
#pragma unroll
                for (int n = 0; n < 4; ++n) {
                    const int r = n * 16 + (lane & 15);
                    const short8 wv = *(const short8*)&smem[1][0][r * 64 + (kc8 ^ (r & 7)) * 8];
                    short8 sv;
#pragma unroll
                    for (int j = 0; j < 8; ++j) {
                        const float wf = bf2f((ushort)wv[j]);
                        sv[j] = (short)f2bf(fmaxf(wf + bb[j], 0.f) - fmaxf(bb[j], 0.f));
                    }
                    bw[n] = sv;
                }
#pragma unroll
                for (int m = 0; m < 4; ++m)
#pragma unroll
                    for (int n = 0; n < 4; ++n)
                        acc[m][n] = __builtin_amdgcn_mfma_f32_16x16x32_bf16(
                            av2[m], bw[n], acc[m][n], 0, 0, 0);
            }
        }
    }

    // epilogue: sum the 4 wave-accumulators through LDS (staging reused).
    __syncthreads();
    float* facc = (float*)smem;    // 16384 floats = 64 KB
#pragma unroll
    for (int m = 0; m < 4; ++m)
#pragma unroll
        for (int n = 0; n < 4; ++n)
            *(f32x4*)&facc[w * 4096 + (m * 4 + n) * 256 + lane * 4] = acc[m][n];
    __syncthreads();
    // wave w finalizes fragment-row m = w.
#pragma unroll
    for (int n = 0; n < 4; ++n) {
        f32x4 s = *(const f32x4*)&facc[(w * 4 + n) * 256 + lane * 4];
#pragma unroll
        for (int wp = 1; wp < 4; ++wp) {
            const f32x4 v = *(const f32x4*)&facc[wp * 4096 + (w * 4 + n) * 256 + lane * 4];
            s.x += v.x; s.y += v.y; s.z += v.z; s.w += v.w;
        }
        const int srow = s0 + w * 16 + (lane >> 4) * 4;
        const int icol = i0 + n * 16 + (lane & 15);
        outp[(size_t)(srow + 0) * INN + icol] = s.x;
        outp[(size_t)(srow + 1) * INN + icol] = s.y;
        outp[(size_t)(srow + 2) * INN + icol] = s.z;
        outp[(size_t)(srow + 3) * INN + icol] = s.w;
    }
}

// ---------------------------------------------------------------------------
extern "C" void kernel_launch(void* const* d_in, const int* in_sizes, int n_in,
                              void* d_out, int out_size, void* d_ws, size_t ws_size,
                              hipStream_t stream) {
    const float* uA    = (const float*)d_in[0];
    const float* W     = (const float*)d_in[1];
    const float* Bias  = (const float*)d_in[2];
    const float* Lb    = (const float*)d_in[3];
    const float* Ub    = (const float*)d_in[4];
    const float* Alpha = (const float*)d_in[5];
    float* outp = (float*)d_out;

    char* ws = (char*)d_ws;
    unsigned long long* rowmask = (unsigned long long*)ws;       // 4 KB
    ushort* A1 = (ushort*)(ws + 4096);                           // 4 MB
    ushort* A2 = (ushort*)(ws + 4096 + (1u << 22));              // 4 MB
    ushort* WT = (ushort*)(ws + 4096 + (2u << 22));              // 32 MB

    prep<<<4608, 256, 0, stream>>>(uA, W, Bias, Lb, Ub, Alpha, A1, A2, WT,
                                   rowmask, outp + (size_t)SPECN * INN);
    gemm<<<512, 256, 0, stream>>>(A1, A2, WT, Bias, rowmask, outp);
}